// Round 3
// 141.005 us; speedup vs baseline: 1.0072x; 1.0072x over previous
//
#include <hip/hip_runtime.h>
#include <stdint.h>

#define B_ROWS 1048576
#define STAT_BLOCKS 512
#define MAIN_BLOCKS 2048            // 256 thr x 2 rows

typedef __fp16 h2 __attribute__((ext_vector_type(2)));

// ws float layout:
//  [0 .. 8)              final BN scale  sc[8]   (written by bn_finalize)
//  [8 .. 16)             final BN shift  sh[8]
//  [16 .. 16+8192)       per-block bn partials: 512 blocks x 16 floats
//  [8208 .. 8578)        packed f16x2 weights (uint32), 370 dwords
//  [8578 .. 8643)        f32 biases, 65 floats
#define PART_OFF 16
#define WPK_OFF 8208
#define BIA_OFF 8578
#define W_FM 0
#define W_C1 64
#define W_P1 192
#define W_C2 288
#define W_P2 336
#define W_C3 352
#define W_R  360
#define W_H  368
#define B_FM 0
#define B_C1 16
#define B_P1 32
#define B_C2 44
#define B_P2 52
#define B_C3 56
#define B_R  60
#define B_H  64

__device__ __forceinline__ float exp_tanh(float x) {   // LUT fill only
    float e = __builtin_amdgcn_exp2f(x * 2.8853900817779268f);
    return 1.0f - 2.0f * __builtin_amdgcn_rcpf(e + 1.0f);
}

__device__ __forceinline__ float fast_sigmoid(float x) {
    float e = __builtin_amdgcn_exp2f(x * -1.4426950408889634f);
    return __builtin_amdgcn_rcpf(1.0f + e);
}

// ---- raw weight packing (no BN fold), used by bn_stats block 0 ----------------
template<int DIN, int DOUT>
__device__ void pack_layer(const float* __restrict__ w, const float* __restrict__ b,
                           uint32_t* __restrict__ wdst, float* __restrict__ bdst) {
    for (int idx = threadIdx.x; idx < DOUT * (DIN / 2); idx += blockDim.x) {
        int j = idx / (DIN / 2), i2 = idx % (DIN / 2);
        h2 h;
        h.x = (__fp16)w[(2 * i2) * DOUT + j];
        h.y = (__fp16)w[(2 * i2 + 1) * DOUT + j];
        wdst[j * (DIN / 2) + i2] = __builtin_bit_cast(uint32_t, h);
    }
    for (int j = threadIdx.x; j < DOUT; j += blockDim.x) bdst[j] = b[j];
}

// ---------------- pass 1: partials (512 blocks) + block0 packs weights ---------
__global__ __launch_bounds__(256) void bn_stats(
    const float* __restrict__ x, float* __restrict__ ws,
    const float* __restrict__ w_fm, const float* __restrict__ b_fm,
    const float* __restrict__ w_c1, const float* __restrict__ b_c1,
    const float* __restrict__ w_p1, const float* __restrict__ b_p1,
    const float* __restrict__ w_c2, const float* __restrict__ b_c2,
    const float* __restrict__ w_p2, const float* __restrict__ b_p2,
    const float* __restrict__ w_c3, const float* __restrict__ b_c3,
    const float* __restrict__ w_r,  const float* __restrict__ b_r,
    const float* __restrict__ w_h,  const float* __restrict__ b_h)
{
    const int tid = blockIdx.x * 256 + threadIdx.x;   // 0..131071
    float s[8], q[8];
#pragma unroll
    for (int c = 0; c < 8; ++c) { s[c] = 0.f; q[c] = 0.f; }
    const float4* x4 = (const float4*)x;
#pragma unroll
    for (int k = 0; k < 8; ++k) {
        int r = tid + k * 131072;
        float4 a = x4[2 * r];
        float4 b = x4[2 * r + 1];
        s[0] += a.x; s[1] += a.y; s[2] += a.z; s[3] += a.w;
        s[4] += b.x; s[5] += b.y; s[6] += b.z; s[7] += b.w;
        q[0] += a.x * a.x; q[1] += a.y * a.y; q[2] += a.z * a.z; q[3] += a.w * a.w;
        q[4] += b.x * b.x; q[5] += b.y * b.y; q[6] += b.z * b.z; q[7] += b.w * b.w;
    }
#pragma unroll
    for (int off = 32; off > 0; off >>= 1) {
#pragma unroll
        for (int c = 0; c < 8; ++c) {
            s[c] += __shfl_down(s[c], off);
            q[c] += __shfl_down(q[c], off);
        }
    }
    __shared__ float red[4][16];
    const int lane = threadIdx.x & 63;
    const int wave = threadIdx.x >> 6;
    if (lane == 0) {
#pragma unroll
        for (int c = 0; c < 8; ++c) { red[wave][c] = s[c]; red[wave][8 + c] = q[c]; }
    }
    __syncthreads();
    if (threadIdx.x < 16) {
        float acc = red[0][threadIdx.x] + red[1][threadIdx.x] +
                    red[2][threadIdx.x] + red[3][threadIdx.x];
        ws[PART_OFF + blockIdx.x * 16 + threadIdx.x] = acc;   // plain store
    }
    // block 0: pack all weights (independent of stats)
    if (blockIdx.x == 0) {
        uint32_t* wpk = (uint32_t*)(ws + WPK_OFF);
        float*    bpk = ws + BIA_OFF;
        pack_layer<8, 16>(w_fm, b_fm, wpk + W_FM, bpk + B_FM);
        pack_layer<16,16>(w_c1, b_c1, wpk + W_C1, bpk + B_C1);
        pack_layer<16,12>(w_p1, b_p1, wpk + W_P1, bpk + B_P1);
        pack_layer<12, 8>(w_c2, b_c2, wpk + W_C2, bpk + B_C2);
        pack_layer<8,  4>(w_p2, b_p2, wpk + W_P2, bpk + B_P2);
        pack_layer<4,  4>(w_c3, b_c3, wpk + W_C3, bpk + B_C3);
        pack_layer<4,  4>(w_r,  b_r,  wpk + W_R,  bpk + B_R);
        pack_layer<4,  1>(w_h,  b_h,  wpk + W_H,  bpk + B_H);
    }
}

// ---------------- pass 1.5: one block reduces partials -> sc/sh ----------------
__global__ __launch_bounds__(256) void bn_finalize(
    const float* __restrict__ bn_g, const float* __restrict__ bn_b,
    float* __restrict__ ws)
{
    __shared__ float accs[16][17];
    const int f = threadIdx.x & 15;
    const int chunk = threadIdx.x >> 4;          // 0..15, each sums 32 blocks
    const float* p = ws + PART_OFF + (chunk * 32) * 16 + f;
    float a = 0.f;
#pragma unroll 8
    for (int b = 0; b < 32; ++b) a += p[b * 16];
    accs[chunk][f] = a;
    __syncthreads();
    if (threadIdx.x < 16) {
        float t = 0.f;
#pragma unroll
        for (int c = 0; c < 16; ++c) t += accs[c][threadIdx.x];
        accs[0][threadIdx.x] = t;
    }
    __syncthreads();
    if (threadIdx.x < 8) {
        const float invB = 1.0f / (float)B_ROWS;
        int c = threadIdx.x;
        float mu  = accs[0][c] * invB;
        float var = fmaf(-mu, mu, accs[0][8 + c] * invB);
        float sv  = bn_g[c] * rsqrtf(var + 1e-5f);
        ws[c]     = sv;
        ws[8 + c] = fmaf(-mu, sv, bn_b[c]);
    }
}

// ------- nearest-entry tanh LUT: 8192 f16 centers on [-4,4], h = 1/1024 --------
__device__ __forceinline__ uint32_t lut_idx(float x) {
    float t = fmaf(x, 1024.0f, 4096.0f);                   // [-4,4] -> [0,8192)
    t = __builtin_amdgcn_fmed3f(t, 0.0f, 8191.0f);         // clamp tails
    return (uint32_t)t;                                    // trunc -> interval idx
}

// ---------------- dot2 single-row layer ----------------------------------------
template<int DIN, int DOUT>
__device__ __forceinline__ void layer_dot1(const h2* __restrict__ apk,
                                           float* __restrict__ o,
                                           const uint32_t* __restrict__ wpk,
                                           const float* __restrict__ bias) {
#pragma unroll
    for (int j = 0; j < DOUT; ++j) {
        float acc = bias[j];
#pragma unroll
        for (int i2 = 0; i2 < DIN / 2; ++i2) {
            h2 w = __builtin_bit_cast(h2, wpk[j * (DIN / 2) + i2]);
            acc = __builtin_amdgcn_fdot2(apk[i2], w, acc, false);
        }
        o[j] = acc;
    }
}

template<int N>
__device__ __forceinline__ void tanh_pack1(const float* __restrict__ in,
                                           h2* __restrict__ pk,
                                           const uint16_t* __restrict__ lut16) {
#pragma unroll
    for (int k = 0; k < N / 2; ++k) {
        uint32_t v0 = lut16[lut_idx(in[2 * k])];
        uint32_t v1 = lut16[lut_idx(in[2 * k + 1])];
        pk[k] = __builtin_bit_cast(h2, v0 | (v1 << 16));
    }
}

// ---------------- full per-row forward chain -----------------------------------
__device__ __forceinline__ float row_forward(float4 x0, float4 x1,
        const float* __restrict__ sc, const float* __restrict__ sh,
        const uint32_t* __restrict__ wpk, const float* __restrict__ bpk,
        const uint16_t* __restrict__ lut16) {
    float n[8];
    n[0] = fmaf(x0.x, sc[0], sh[0]); n[1] = fmaf(x0.y, sc[1], sh[1]);
    n[2] = fmaf(x0.z, sc[2], sh[2]); n[3] = fmaf(x0.w, sc[3], sh[3]);
    n[4] = fmaf(x1.x, sc[4], sh[4]); n[5] = fmaf(x1.y, sc[5], sh[5]);
    n[6] = fmaf(x1.z, sc[6], sh[6]); n[7] = fmaf(x1.w, sc[7], sh[7]);
    h2 a[4];
#pragma unroll
    for (int k = 0; k < 4; ++k)
        a[k] = __builtin_amdgcn_cvt_pkrtz(n[2 * k], n[2 * k + 1]);

    float o1[16]; h2 p1[8];
    layer_dot1<8, 16>(a, o1, wpk + W_FM, bpk + B_FM);
    tanh_pack1<16>(o1, p1, lut16);
    float o2[16]; h2 p2[8];
    layer_dot1<16,16>(p1, o2, wpk + W_C1, bpk + B_C1);
    tanh_pack1<16>(o2, p2, lut16);
    float o3[12]; h2 p3[6];
    layer_dot1<16,12>(p2, o3, wpk + W_P1, bpk + B_P1);
    tanh_pack1<12>(o3, p3, lut16);
    float o4[8]; h2 p4[4];
    layer_dot1<12, 8>(p3, o4, wpk + W_C2, bpk + B_C2);
    tanh_pack1<8>(o4, p4, lut16);
    float o5[4]; h2 p5[2];
    layer_dot1<8,  4>(p4, o5, wpk + W_P2, bpk + B_P2);
    tanh_pack1<4>(o5, p5, lut16);
    float c4[4];
    layer_dot1<4,  4>(p5, c4, wpk + W_C3, bpk + B_C3);

    uint32_t u[4]; float f[4];
#pragma unroll
    for (int j = 0; j < 4; ++j) {
        u[j] = lut16[lut_idx(c4[j])];
        f[j] = (float)__builtin_bit_cast(__fp16, (uint16_t)u[j]);
    }
    h2 pc[2];
    pc[0] = __builtin_bit_cast(h2, u[0] | (u[1] << 16));
    pc[1] = __builtin_bit_cast(h2, u[2] | (u[3] << 16));
    float r4[4];
    layer_dot1<4,  4>(pc, r4, wpk + W_R, bpk + B_R);
#pragma unroll
    for (int j = 0; j < 4; ++j) f[j] += fmaxf(r4[j], 0.f);
    h2 ph[2];
    ph[0] = __builtin_amdgcn_cvt_pkrtz(f[0], f[1]);
    ph[1] = __builtin_amdgcn_cvt_pkrtz(f[2], f[3]);
    float oh[1];
    layer_dot1<4,  1>(ph, oh, wpk + W_H, bpk + B_H);
    return fast_sigmoid(oh[0]);
}

// ---------------- pass 2: normalize + MLP chain --------------------------------
// LDS 16.4 KB (f16 LUT) -> 9 blocks/CU LDS-limit; launch_bounds(256,6) caps
// VGPR<=85 (est. live ~70) -> 6 blocks/CU, 24 waves/CU (was 4 blocks / 16 waves).
__global__ __launch_bounds__(256, 6) void qcnn_main(
    const float* __restrict__ x, const float* __restrict__ ws,
    float* __restrict__ out)
{
    // issue x loads first (overlap LUT fill)
    const int tid = blockIdx.x * 256 + threadIdx.x;
    const int r0 = tid, r1 = tid + (B_ROWS / 2);
    const float4* x4 = (const float4*)x;
    float4 xa0 = x4[2 * r0], xa1 = x4[2 * r0 + 1];
    float4 xb0 = x4[2 * r1], xb1 = x4[2 * r1 + 1];

    __shared__ uint16_t lut16[8192];
    {
        const float h = 0.0009765625f;        // 1/1024
        uint32_t* l32 = (uint32_t*)lut16;
#pragma unroll
        for (int k = 0; k < 16; ++k) {
            int i2 = threadIdx.x + k * 256;   // dword index 0..4095
            float c0 = fmaf((float)(2 * i2) + 0.5f, h, -4.0f);
            float c1 = fmaf((float)(2 * i2 + 1) + 0.5f, h, -4.0f);
            __fp16 h0 = (__fp16)exp_tanh(c0);
            __fp16 h1 = (__fp16)exp_tanh(c1);
            l32[i2] = (uint32_t)__builtin_bit_cast(uint16_t, h0)
                    | ((uint32_t)__builtin_bit_cast(uint16_t, h1) << 16);
        }
    }
    // uniform scalar prologue: final sc/sh from bn_finalize
    float sc[8], sh[8];
#pragma unroll
    for (int c = 0; c < 8; ++c) { sc[c] = ws[c]; sh[c] = ws[8 + c]; }
    __syncthreads();

    const uint32_t* wpk = (const uint32_t*)(ws + WPK_OFF);
    const float*    bpk = ws + BIA_OFF;

    out[r0] = row_forward(xa0, xa1, sc, sh, wpk, bpk, lut16);
    out[r1] = row_forward(xb0, xb1, sc, sh, wpk, bpk, lut16);
}

extern "C" void kernel_launch(void* const* d_in, const int* in_sizes, int n_in,
                              void* d_out, int out_size, void* d_ws, size_t ws_size,
                              hipStream_t stream) {
    const float* x    = (const float*)d_in[0];
    const float* bn_g = (const float*)d_in[1];
    const float* bn_b = (const float*)d_in[2];
    const float* w_fm = (const float*)d_in[3];
    const float* b_fm = (const float*)d_in[4];
    const float* w_c1 = (const float*)d_in[5];
    const float* b_c1 = (const float*)d_in[6];
    const float* w_p1 = (const float*)d_in[7];
    const float* b_p1 = (const float*)d_in[8];
    const float* w_c2 = (const float*)d_in[9];
    const float* b_c2 = (const float*)d_in[10];
    const float* w_p2 = (const float*)d_in[11];
    const float* b_p2 = (const float*)d_in[12];
    const float* w_c3 = (const float*)d_in[13];
    const float* b_c3 = (const float*)d_in[14];
    const float* w_r  = (const float*)d_in[15];
    const float* b_r  = (const float*)d_in[16];
    const float* w_h  = (const float*)d_in[17];
    const float* b_h  = (const float*)d_in[18];
    float* out = (float*)d_out;
    float* ws  = (float*)d_ws;

    bn_stats<<<STAT_BLOCKS, 256, 0, stream>>>(
        x, ws, w_fm, b_fm, w_c1, b_c1, w_p1, b_p1, w_c2, b_c2,
        w_p2, b_p2, w_c3, b_c3, w_r, b_r, w_h, b_h);
    bn_finalize<<<1, 256, 0, stream>>>(bn_g, bn_b, ws);
    qcnn_main<<<MAIN_BLOCKS, 256, 0, stream>>>(x, ws, out);
}

// Round 4
// 139.178 us; speedup vs baseline: 1.0204x; 1.0131x over previous
//
#include <hip/hip_runtime.h>
#include <stdint.h>

#define B_ROWS 1048576
#define STAT_BLOCKS 512
#define MAIN_BLOCKS 2048            // 256 thr x 2 rows

typedef __fp16 h2 __attribute__((ext_vector_type(2)));

// ws float layout:
//  [16 .. 16+8192)       per-block bn partials: 512 blocks x 16 floats
//  [8208 .. 8578)        packed f16x2 weights (uint32), 370 dwords
//                        (fm layer BN-folded in f32 by bn_finalize)
//  [8578 .. 8643)        f32 biases, 65 floats
#define PART_OFF 16
#define WPK_OFF 8208
#define BIA_OFF 8578
#define W_FM 0
#define W_C1 64
#define W_P1 192
#define W_C2 288
#define W_P2 336
#define W_C3 352
#define W_R  360
#define W_H  368
#define B_FM 0
#define B_C1 16
#define B_P1 32
#define B_C2 44
#define B_P2 52
#define B_C3 56
#define B_R  60
#define B_H  64

// tanh(x) = 1 - 2/(exp2(2*log2e*x) + 1)  — 2 TRANS + 3 VALU, no LDS
__device__ __forceinline__ float exp_tanh(float x) {
    float e = __builtin_amdgcn_exp2f(x * 2.8853900817779268f);
    return 1.0f - 2.0f * __builtin_amdgcn_rcpf(e + 1.0f);
}

__device__ __forceinline__ float fast_sigmoid(float x) {
    float e = __builtin_amdgcn_exp2f(x * -1.4426950408889634f);
    return __builtin_amdgcn_rcpf(1.0f + e);
}

// ---- raw weight packing, used by bn_stats block 0 -----------------------------
template<int DIN, int DOUT>
__device__ void pack_layer(const float* __restrict__ w, const float* __restrict__ b,
                           uint32_t* __restrict__ wdst, float* __restrict__ bdst) {
    for (int idx = threadIdx.x; idx < DOUT * (DIN / 2); idx += blockDim.x) {
        int j = idx / (DIN / 2), i2 = idx % (DIN / 2);
        h2 h;
        h.x = (__fp16)w[(2 * i2) * DOUT + j];
        h.y = (__fp16)w[(2 * i2 + 1) * DOUT + j];
        wdst[j * (DIN / 2) + i2] = __builtin_bit_cast(uint32_t, h);
    }
    for (int j = threadIdx.x; j < DOUT; j += blockDim.x) bdst[j] = b[j];
}

// ---------------- pass 1: partials (512 blocks) + block0 packs weights ---------
__global__ __launch_bounds__(256) void bn_stats(
    const float* __restrict__ x, float* __restrict__ ws,
    const float* __restrict__ w_c1, const float* __restrict__ b_c1,
    const float* __restrict__ w_p1, const float* __restrict__ b_p1,
    const float* __restrict__ w_c2, const float* __restrict__ b_c2,
    const float* __restrict__ w_p2, const float* __restrict__ b_p2,
    const float* __restrict__ w_c3, const float* __restrict__ b_c3,
    const float* __restrict__ w_r,  const float* __restrict__ b_r,
    const float* __restrict__ w_h,  const float* __restrict__ b_h)
{
    const int tid = blockIdx.x * 256 + threadIdx.x;   // 0..131071
    float s[8], q[8];
#pragma unroll
    for (int c = 0; c < 8; ++c) { s[c] = 0.f; q[c] = 0.f; }
    const float4* x4 = (const float4*)x;
#pragma unroll
    for (int k = 0; k < 8; ++k) {
        int r = tid + k * 131072;
        float4 a = x4[2 * r];
        float4 b = x4[2 * r + 1];
        s[0] += a.x; s[1] += a.y; s[2] += a.z; s[3] += a.w;
        s[4] += b.x; s[5] += b.y; s[6] += b.z; s[7] += b.w;
        q[0] += a.x * a.x; q[1] += a.y * a.y; q[2] += a.z * a.z; q[3] += a.w * a.w;
        q[4] += b.x * b.x; q[5] += b.y * b.y; q[6] += b.z * b.z; q[7] += b.w * b.w;
    }
#pragma unroll
    for (int off = 32; off > 0; off >>= 1) {
#pragma unroll
        for (int c = 0; c < 8; ++c) {
            s[c] += __shfl_down(s[c], off);
            q[c] += __shfl_down(q[c], off);
        }
    }
    __shared__ float red[4][16];
    const int lane = threadIdx.x & 63;
    const int wave = threadIdx.x >> 6;
    if (lane == 0) {
#pragma unroll
        for (int c = 0; c < 8; ++c) { red[wave][c] = s[c]; red[wave][8 + c] = q[c]; }
    }
    __syncthreads();
    if (threadIdx.x < 16) {
        float acc = red[0][threadIdx.x] + red[1][threadIdx.x] +
                    red[2][threadIdx.x] + red[3][threadIdx.x];
        ws[PART_OFF + blockIdx.x * 16 + threadIdx.x] = acc;
    }
    // block 0: pack layers c1..h (fm is packed BN-folded by bn_finalize)
    if (blockIdx.x == 0) {
        uint32_t* wpk = (uint32_t*)(ws + WPK_OFF);
        float*    bpk = ws + BIA_OFF;
        pack_layer<16,16>(w_c1, b_c1, wpk + W_C1, bpk + B_C1);
        pack_layer<16,12>(w_p1, b_p1, wpk + W_P1, bpk + B_P1);
        pack_layer<12, 8>(w_c2, b_c2, wpk + W_C2, bpk + B_C2);
        pack_layer<8,  4>(w_p2, b_p2, wpk + W_P2, bpk + B_P2);
        pack_layer<4,  4>(w_c3, b_c3, wpk + W_C3, bpk + B_C3);
        pack_layer<4,  4>(w_r,  b_r,  wpk + W_R,  bpk + B_R);
        pack_layer<4,  1>(w_h,  b_h,  wpk + W_H,  bpk + B_H);
    }
}

// ---------------- pass 1.5: reduce partials, fold BN into fm layer -------------
__global__ __launch_bounds__(256) void bn_finalize(
    const float* __restrict__ bn_g, const float* __restrict__ bn_b,
    const float* __restrict__ w_fm, const float* __restrict__ b_fm,
    float* __restrict__ ws)
{
    __shared__ float accs[16][17];
    __shared__ float scs[8], shs[8];
    const int f = threadIdx.x & 15;
    const int chunk = threadIdx.x >> 4;          // 0..15, each sums 32 blocks
    const float* p = ws + PART_OFF + (chunk * 32) * 16 + f;
    float a = 0.f;
#pragma unroll 8
    for (int b = 0; b < 32; ++b) a += p[b * 16];
    accs[chunk][f] = a;
    __syncthreads();
    if (threadIdx.x < 16) {
        float t = 0.f;
#pragma unroll
        for (int c = 0; c < 16; ++c) t += accs[c][threadIdx.x];
        accs[0][threadIdx.x] = t;
    }
    __syncthreads();
    if (threadIdx.x < 8) {
        const float invB = 1.0f / (float)B_ROWS;
        int c = threadIdx.x;
        float mu  = accs[0][c] * invB;
        float var = fmaf(-mu, mu, accs[0][8 + c] * invB);
        float sv  = bn_g[c] * rsqrtf(var + 1e-5f);
        scs[c] = sv;
        shs[c] = fmaf(-mu, sv, bn_b[c]);
    }
    __syncthreads();
    // fold: W'[i][j] = W[i][j]*sc[i] (f32 mul, then one f16 round)
    if (threadIdx.x < 64) {
        int j = threadIdx.x >> 2, i2 = threadIdx.x & 3;
        h2 h;
        h.x = (__fp16)(w_fm[(2 * i2) * 16 + j]     * scs[2 * i2]);
        h.y = (__fp16)(w_fm[(2 * i2 + 1) * 16 + j] * scs[2 * i2 + 1]);
        ((uint32_t*)(ws + WPK_OFF))[W_FM + j * 4 + i2] = __builtin_bit_cast(uint32_t, h);
    }
    // fold: b'[j] = b[j] + sum_i sh[i]*W[i][j]  (kept f32)
    if (threadIdx.x < 16) {
        int j = threadIdx.x;
        float acc = b_fm[j];
#pragma unroll
        for (int i = 0; i < 8; ++i) acc = fmaf(shs[i], w_fm[i * 16 + j], acc);
        (ws + BIA_OFF)[B_FM + j] = acc;
    }
}

// ---------------- dot2 single-row layer ----------------------------------------
template<int DIN, int DOUT>
__device__ __forceinline__ void layer_dot1(const h2* __restrict__ apk,
                                           float* __restrict__ o,
                                           const uint32_t* __restrict__ wpk,
                                           const float* __restrict__ bias) {
#pragma unroll
    for (int j = 0; j < DOUT; ++j) {
        float acc = bias[j];
#pragma unroll
        for (int i2 = 0; i2 < DIN / 2; ++i2) {
            h2 w = __builtin_bit_cast(h2, wpk[j * (DIN / 2) + i2]);
            acc = __builtin_amdgcn_fdot2(apk[i2], w, acc, false);
        }
        o[j] = acc;
    }
}

template<int N>
__device__ __forceinline__ void tanh_pack1(const float* __restrict__ in,
                                           h2* __restrict__ pk) {
#pragma unroll
    for (int k = 0; k < N / 2; ++k) {
        float t0 = exp_tanh(in[2 * k]);
        float t1 = exp_tanh(in[2 * k + 1]);
        pk[k] = __builtin_amdgcn_cvt_pkrtz(t0, t1);
    }
}

// ---------------- full per-row forward chain (BN pre-folded into fm) -----------
__device__ __forceinline__ float row_forward(float4 x0, float4 x1,
        const uint32_t* __restrict__ wpk, const float* __restrict__ bpk) {
    h2 a[4];
    a[0] = __builtin_amdgcn_cvt_pkrtz(x0.x, x0.y);
    a[1] = __builtin_amdgcn_cvt_pkrtz(x0.z, x0.w);
    a[2] = __builtin_amdgcn_cvt_pkrtz(x1.x, x1.y);
    a[3] = __builtin_amdgcn_cvt_pkrtz(x1.z, x1.w);

    float o1[16]; h2 p1[8];
    layer_dot1<8, 16>(a, o1, wpk + W_FM, bpk + B_FM);
    tanh_pack1<16>(o1, p1);
    float o2[16]; h2 p2[8];
    layer_dot1<16,16>(p1, o2, wpk + W_C1, bpk + B_C1);
    tanh_pack1<16>(o2, p2);
    float o3[12]; h2 p3[6];
    layer_dot1<16,12>(p2, o3, wpk + W_P1, bpk + B_P1);
    tanh_pack1<12>(o3, p3);
    float o4[8]; h2 p4[4];
    layer_dot1<12, 8>(p3, o4, wpk + W_C2, bpk + B_C2);
    tanh_pack1<8>(o4, p4);
    float o5[4]; h2 p5[2];
    layer_dot1<8,  4>(p4, o5, wpk + W_P2, bpk + B_P2);
    tanh_pack1<4>(o5, p5);
    float c4[4];
    layer_dot1<4,  4>(p5, c4, wpk + W_C3, bpk + B_C3);

    float f[4];
#pragma unroll
    for (int j = 0; j < 4; ++j) f[j] = exp_tanh(c4[j]);
    h2 pc[2];
    pc[0] = __builtin_amdgcn_cvt_pkrtz(f[0], f[1]);
    pc[1] = __builtin_amdgcn_cvt_pkrtz(f[2], f[3]);
    float r4[4];
    layer_dot1<4,  4>(pc, r4, wpk + W_R, bpk + B_R);
#pragma unroll
    for (int j = 0; j < 4; ++j) f[j] += fmaxf(r4[j], 0.f);
    h2 ph[2];
    ph[0] = __builtin_amdgcn_cvt_pkrtz(f[0], f[1]);
    ph[1] = __builtin_amdgcn_cvt_pkrtz(f[2], f[3]);
    float oh[1];
    layer_dot1<4,  1>(ph, oh, wpk + W_H, bpk + B_H);
    return fast_sigmoid(oh[0]);
}

// ---------------- pass 2: MLP chain, no LDS, TRANS-pipe tanh -------------------
// No __shared__ -> occupancy is VGPR-bound; (256,6) caps VGPR<=85 (est live ~60)
// -> 6 blocks/CU, 24 waves/CU. tanh on TRANS pipe (per-SIMD) instead of the
// per-CU LDS pipe that round-3 showed to be the saturated resource.
__global__ __launch_bounds__(256, 6) void qcnn_main(
    const float* __restrict__ x, const float* __restrict__ ws,
    float* __restrict__ out)
{
    const int tid = blockIdx.x * 256 + threadIdx.x;
    const int r0 = tid, r1 = tid + (B_ROWS / 2);
    const float4* x4 = (const float4*)x;
    float4 xa0 = x4[2 * r0], xa1 = x4[2 * r0 + 1];
    float4 xb0 = x4[2 * r1], xb1 = x4[2 * r1 + 1];

    const uint32_t* wpk = (const uint32_t*)(ws + WPK_OFF);
    const float*    bpk = ws + BIA_OFF;

    out[r0] = row_forward(xa0, xa1, wpk, bpk);
    out[r1] = row_forward(xb0, xb1, wpk, bpk);
}

extern "C" void kernel_launch(void* const* d_in, const int* in_sizes, int n_in,
                              void* d_out, int out_size, void* d_ws, size_t ws_size,
                              hipStream_t stream) {
    const float* x    = (const float*)d_in[0];
    const float* bn_g = (const float*)d_in[1];
    const float* bn_b = (const float*)d_in[2];
    const float* w_fm = (const float*)d_in[3];
    const float* b_fm = (const float*)d_in[4];
    const float* w_c1 = (const float*)d_in[5];
    const float* b_c1 = (const float*)d_in[6];
    const float* w_p1 = (const float*)d_in[7];
    const float* b_p1 = (const float*)d_in[8];
    const float* w_c2 = (const float*)d_in[9];
    const float* b_c2 = (const float*)d_in[10];
    const float* w_p2 = (const float*)d_in[11];
    const float* b_p2 = (const float*)d_in[12];
    const float* w_c3 = (const float*)d_in[13];
    const float* b_c3 = (const float*)d_in[14];
    const float* w_r  = (const float*)d_in[15];
    const float* b_r  = (const float*)d_in[16];
    const float* w_h  = (const float*)d_in[17];
    const float* b_h  = (const float*)d_in[18];
    float* out = (float*)d_out;
    float* ws  = (float*)d_ws;

    bn_stats<<<STAT_BLOCKS, 256, 0, stream>>>(
        x, ws, w_c1, b_c1, w_p1, b_p1, w_c2, b_c2,
        w_p2, b_p2, w_c3, b_c3, w_r, b_r, w_h, b_h);
    bn_finalize<<<1, 256, 0, stream>>>(bn_g, bn_b, w_fm, b_fm, ws);
    qcnn_main<<<MAIN_BLOCKS, 256, 0, stream>>>(x, ws, out);
}